// Round 3
// baseline (165.143 us; speedup 1.0000x reference)
//
#include <hip/hip_runtime.h>
#include <math.h>

#define BB 8
#define TT 96
#define SS 192
#define DIN 512
#define DM 512

typedef short short8 __attribute__((ext_vector_type(8)));
typedef float f32x4 __attribute__((ext_vector_type(4)));

__device__ __forceinline__ unsigned short f2bf(float f) {
    unsigned int u = __float_as_uint(f);
    unsigned int r = u + 0x7FFFu + ((u >> 16) & 1u);   // RNE
    return (unsigned short)(r >> 16);
}
__device__ __forceinline__ float bf2f(unsigned short h) {
    return __uint_as_float(((unsigned int)h) << 16);
}

// pack 2 fp32 -> 2 bf16 (RNE), pure software path (element-independent:
// immune to any HW pack-order semantics).
__device__ __forceinline__ unsigned int pack2bf(float lo, float hi) {
    return ((unsigned int)f2bf(hi) << 16) | (unsigned int)f2bf(lo);
}

// load 8 consecutive fp32 and convert to a bf16x8 MFMA fragment (k-ascending)
__device__ __forceinline__ short8 load_cvt8(const float* __restrict__ p) {
    float4 a = *(const float4*)p;
    float4 b = *(const float4*)(p + 4);
    union { unsigned int u[4]; short8 s; } r;
    r.u[0] = pack2bf(a.x, a.y);
    r.u[1] = pack2bf(a.z, a.w);
    r.u[2] = pack2bf(b.x, b.y);
    r.u[3] = pack2bf(b.z, b.w);
    return r.s;
}

// ---------------- proj: wq = inputs@Wq^T ; uh = mems@Wc^T + bc ----------------
// LDS-free: each wave owns a 16x32 output tile; fragments loaded straight from
// global (wave = 16 rows x 128B = full cache lines), fp32->bf16 in-register.
// No barriers anywhere -> compiler software-pipelines loads across K.
// wave-tiles: wq 48x16=768, uh 96x16=1536 -> 2304 waves = 576 blocks.
__global__ __launch_bounds__(256) void proj_gemm(
    const float* __restrict__ inputs, const float* __restrict__ mems,
    const float* __restrict__ Wq, const float* __restrict__ Wc,
    const float* __restrict__ bc,
    unsigned short* __restrict__ wq_o, unsigned short* __restrict__ uh_o)
{
    const int wid_g = blockIdx.x * 4 + (threadIdx.x >> 6);
    const int lane = threadIdx.x & 63;
    const int quad = lane >> 4, mrow = lane & 15;

    const float* A; const float* W; const float* bias; unsigned short* out;
    int wr, wc;
    if (wid_g < 768) {           // wq: M=768
        A = inputs; W = Wq; bias = nullptr; out = wq_o;
        wr = wid_g >> 4; wc = wid_g & 15;
    } else {                      // uh: M=1536
        int id = wid_g - 768;
        A = mems; W = Wc; bias = bc; out = uh_o;
        wr = id >> 4; wc = id & 15;
    }
    const int K = 512;
    const float* arow = A + (size_t)(wr * 16 + mrow) * K + quad * 8;
    const float* w0   = W + (size_t)(wc * 32 + mrow) * K + quad * 8;
    const float* w1   = w0 + 16 * K;

    f32x4 acc0 = {0,0,0,0}, acc1 = {0,0,0,0};
    #pragma unroll 4
    for (int c = 0; c < K / 32; ++c) {
        short8 av = load_cvt8(arow + c * 32);
        short8 b0 = load_cvt8(w0 + c * 32);
        short8 b1 = load_cvt8(w1 + c * 32);
        acc0 = __builtin_amdgcn_mfma_f32_16x16x32_bf16(av, b0, acc0, 0, 0, 0);
        acc1 = __builtin_amdgcn_mfma_f32_16x16x32_bf16(av, b1, acc1, 0, 0, 0);
    }

    f32x4 accs[2] = {acc0, acc1};
    #pragma unroll
    for (int ct = 0; ct < 2; ++ct) {
        int col = wc * 32 + ct * 16 + mrow;
        float bv = bias ? bias[col] : 0.0f;
        #pragma unroll
        for (int rg = 0; rg < 4; ++rg) {
            int rw = wr * 16 + quad * 4 + rg;   // C/D: col=lane&15, row=quad*4+reg
            out[(size_t)rw * DM + col] = f2bf(accs[ct][rg] + bv);
        }
    }
}

// ---------------- attn_h = concat(c, inputs) @ Wout^T + bout ----------------
// M=768, N=512, K=1024 (K1=512 from c_bf (bf16), K2=512 from inputs (fp32)).
// Same LDS-free wave-tile structure: 48x16 = 768 waves = 192 blocks.
__global__ __launch_bounds__(256) void out_gemm(
    const unsigned short* __restrict__ c_bf,
    const float* __restrict__ inputs,
    const float* __restrict__ Wout,
    const float* __restrict__ bout,
    float* __restrict__ attn_h)
{
    const int wid_g = blockIdx.x * 4 + (threadIdx.x >> 6);
    const int lane = threadIdx.x & 63;
    const int quad = lane >> 4, mrow = lane & 15;
    const int wr = wid_g >> 4, wc = wid_g & 15;
    const int KW = DM + DIN;   // 1024

    const unsigned short* a1 = c_bf + (size_t)(wr * 16 + mrow) * DM + quad * 8;
    const float* a2 = inputs + (size_t)(wr * 16 + mrow) * DIN + quad * 8;
    const float* w0 = Wout + (size_t)(wc * 32 + mrow) * KW + quad * 8;
    const float* w1 = w0 + 16 * KW;

    f32x4 acc0 = {0,0,0,0}, acc1 = {0,0,0,0};
    #pragma unroll 4
    for (int c = 0; c < 16; ++c) {          // k in [0,512): c (bf16, no cvt)
        short8 av = *(const short8*)(a1 + c * 32);
        short8 b0 = load_cvt8(w0 + c * 32);
        short8 b1 = load_cvt8(w1 + c * 32);
        acc0 = __builtin_amdgcn_mfma_f32_16x16x32_bf16(av, b0, acc0, 0, 0, 0);
        acc1 = __builtin_amdgcn_mfma_f32_16x16x32_bf16(av, b1, acc1, 0, 0, 0);
    }
    #pragma unroll 4
    for (int c = 0; c < 16; ++c) {          // k in [512,1024): inputs (fp32)
        short8 av = load_cvt8(a2 + c * 32);
        short8 b0 = load_cvt8(w0 + 512 + c * 32);
        short8 b1 = load_cvt8(w1 + 512 + c * 32);
        acc0 = __builtin_amdgcn_mfma_f32_16x16x32_bf16(av, b0, acc0, 0, 0, 0);
        acc1 = __builtin_amdgcn_mfma_f32_16x16x32_bf16(av, b1, acc1, 0, 0, 0);
    }

    f32x4 accs[2] = {acc0, acc1};
    #pragma unroll
    for (int ct = 0; ct < 2; ++ct) {
        int col = wc * 32 + ct * 16 + mrow;
        float bv = bout[col];
        #pragma unroll
        for (int rg = 0; rg < 4; ++rg) {
            int rw = wr * 16 + quad * 4 + rg;
            attn_h[(size_t)rw * DIN + col] = accs[ct][rg] + bv;
        }
    }
}

// ---------------- fused scores + softmax + context ----------------
// one block per (b,t); lane owns m = lane*8..lane*8+8 (q,v in registers)
__global__ __launch_bounds__(256) void attn_core(
    const unsigned short* __restrict__ wq,     // [B*T][DM] bf16
    const unsigned short* __restrict__ uh,     // [B*S][DM] bf16
    const float* __restrict__ v,               // [DM] fp32
    const float* __restrict__ mems,            // [B*S][DM] fp32 (read direct)
    const int* __restrict__ masks,             // [B]
    float* __restrict__ align_out,             // [B*T][S] fp32
    unsigned short* __restrict__ c_out)        // [B*T][DM] bf16
{
    __shared__ float s_align[SS];
    __shared__ float s_stat;
    const int row = blockIdx.x, b = row / TT;
    const int tid = threadIdx.x, lane = tid & 63, wid = tid >> 6;
    const int len = masks[b];

    float qf[8], vf[8];
    {
        short8 q = *(const short8*)(wq + (size_t)row * DM + lane * 8);
        float4 v0 = *(const float4*)(v + lane * 8);
        float4 v1 = *(const float4*)(v + lane * 8 + 4);
        #pragma unroll
        for (int j = 0; j < 8; ++j) qf[j] = bf2f((unsigned short)q[j]);
        vf[0] = v0.x; vf[1] = v0.y; vf[2] = v0.z; vf[3] = v0.w;
        vf[4] = v1.x; vf[5] = v1.y; vf[6] = v1.z; vf[7] = v1.w;
    }

    for (int s = wid; s < SS; s += 4) {
        float val = -INFINITY;
        if (s < len) {
            short8 u = *(const short8*)(uh + ((size_t)b * SS + s) * DM + lane * 8);
            float part = 0.f;
            #pragma unroll
            for (int j = 0; j < 8; ++j) {
                float x = qf[j] + bf2f((unsigned short)u[j]);
                // exact tanh: 1 - 2/(exp2(x*2/ln2)+1)
                float e = __builtin_amdgcn_exp2f(x * 2.885390082f);
                float th = fmaf(-2.f, __builtin_amdgcn_rcpf(e + 1.f), 1.f);
                part = fmaf(vf[j], th, part);
            }
            #pragma unroll
            for (int off = 32; off; off >>= 1)
                part += __shfl_xor(part, off);
            val = part;
        }
        if (lane == 0) s_align[s] = val;
    }
    __syncthreads();

    if (tid < 64) {
        float m = fmaxf(fmaxf(s_align[tid], s_align[tid + 64]), s_align[tid + 128]);
        #pragma unroll
        for (int off = 32; off; off >>= 1) m = fmaxf(m, __shfl_xor(m, off));
        float e0 = __builtin_amdgcn_exp2f((s_align[tid]       - m) * 1.44269504f);
        float e1 = __builtin_amdgcn_exp2f((s_align[tid + 64]  - m) * 1.44269504f);
        float e2 = __builtin_amdgcn_exp2f((s_align[tid + 128] - m) * 1.44269504f);
        s_align[tid] = e0; s_align[tid + 64] = e1; s_align[tid + 128] = e2;
        float sum = e0 + e1 + e2;
        #pragma unroll
        for (int off = 32; off; off >>= 1) sum += __shfl_xor(sum, off);
        if (tid == 0) s_stat = 1.0f / sum;
    }
    __syncthreads();
    const float inv = s_stat;
    if (tid < SS) align_out[(size_t)row * SS + tid] = s_align[tid] * inv;

    // context: thread owns dims 2*tid, 2*tid+1 ; mems read as fp32 (exact)
    float a0 = 0.f, a1 = 0.f;
    const float* mb = mems + (size_t)b * SS * DM;
    for (int s = 0; s < len; ++s) {
        float p = s_align[s];
        float2 mv = *(const float2*)(mb + (size_t)s * DM + tid * 2);
        a0 = fmaf(p, mv.x, a0);
        a1 = fmaf(p, mv.y, a1);
    }
    unsigned int pack = ((unsigned int)f2bf(a1 * inv) << 16) | (unsigned int)f2bf(a0 * inv);
    *(unsigned int*)(c_out + (size_t)row * DM + tid * 2) = pack;
}

extern "C" void kernel_launch(void* const* d_in, const int* in_sizes, int n_in,
                              void* d_out, int out_size, void* d_ws, size_t ws_size,
                              hipStream_t stream) {
    (void)in_sizes; (void)n_in; (void)out_size; (void)ws_size;
    const float* inputs = (const float*)d_in[0];
    const float* mems   = (const float*)d_in[1];
    const int*   masks  = (const int*)  d_in[2];
    const float* Wq     = (const float*)d_in[3];
    const float* Wc     = (const float*)d_in[4];
    const float* bc     = (const float*)d_in[5];
    const float* v      = (const float*)d_in[6];
    const float* Wout   = (const float*)d_in[7];
    const float* bout   = (const float*)d_in[8];

    unsigned short* p = (unsigned short*)d_ws;
    unsigned short* uh_bf = p;            p += 786432;   // [B*S][DM]
    unsigned short* wq_bf = p;            p += 393216;   // [B*T][DM], aliased as c_bf
    unsigned short* c_bf  = wq_bf;  // safe: attn block reads wq[row] before writing c[row]

    float* attn_h    = (float*)d_out;                    // [768][512]
    float* align_out = attn_h + (size_t)BB * TT * DIN;   // [768][192]

    proj_gemm<<<576, 256, 0, stream>>>(inputs, mems, Wq, Wc, bc, wq_bf, uh_bf);
    attn_core<<<BB * TT, 256, 0, stream>>>(wq_bf, uh_bf, v, mems, masks,
                                           align_out, c_bf);
    out_gemm<<<192, 256, 0, stream>>>(c_bf, inputs, Wout, bout, attn_h);
}